// Round 15
// baseline (84.741 us; speedup 1.0000x reference)
//
#include <hip/hip_runtime.h>
#include <math.h>

#define NC 80
#define TCOLS 6

// ANCHORS[scale][anchor][wh]
__device__ __constant__ float c_anch[3][3][2] = {
  {{10.f,13.f},{16.f,30.f},{33.f,23.f}},
  {{30.f,61.f},{62.f,45.f},{59.f,119.f}},
  {{116.f,90.f},{156.f,198.f},{373.f,326.f}}
};

// acc layout (floats) — hot scalars on own 64 B lines; zeroed by k_stream block 0
#define ACC_BOX(s) (0  + 16*(s))
#define ACC_CLS(s) (48 + 16*(s))
#define ACC_NV(s)  (96 + 16*(s))
#define ACC_SEG    144                  // [3*NC sums][3*NC counts]
#define ACC_TOTAL  (144 + 6*NC)         // 624 floats

// ws float offsets
#define S0OFF   1024                    // s0row[9N] : per-row sum of focal0 over 80 cls ch
#define SLOTOFF 8704                    // per-stream-block slots: [0]=obj [1]=corr

// fast transcendentals (v_exp/v_log/v_sqrt); abs err ~1e-6 << 0.47 threshold
__device__ __forceinline__ float fbce0(float x) {   // bce(x,0)
  return fmaxf(x, 0.f) + __logf(1.f + __expf(-fabsf(x)));
}
__device__ __forceinline__ float fbce1(float x) {   // bce(x,1)
  return fmaxf(x, 0.f) - x + __logf(1.f + __expf(-fabsf(x)));
}
__device__ __forceinline__ float ffoc(float ce) {   // (1-e^-ce)^1.5 * ce
  float u = 1.f - __expf(-ce);
  return u * __builtin_amdgcn_sqrtf(u) * ce;
}

// Full coalesced stream of cls+obj channels. Each block owns 128 float4-columns
// (col4 = one (s,b,a,pix4) group). 2 threads per col4 split the 80 cls channels.
// Per block: LDS bitmask of matched cells (built from targets) + pair list
// (local pix -> row id) so S0 lands directly in s0row[row]. Obj: bce0 everywhere,
// -x at matched cells (dedup natural: each element visited once).
__global__ __launch_bounds__(256)
void k_stream(const float* __restrict__ p0, const float* __restrict__ p1,
              const float* __restrict__ p2, const float* __restrict__ tgt,
              int N, int B, float* __restrict__ ws) {
  const int tid = threadIdx.x;
  const int c0  = blockIdx.x * 128;            // col4 base of this block
  float* acc   = ws;
  float* s0row = ws + S0OFF;
  float* slot  = ws + SLOTOFF + blockIdx.x * 16;

  const int b4_1 = B*3*1600;                   // s0 col4 count (76800 @ B=16)
  const int b4_2 = b4_1 + B*3*400;             // + s1 (96000)
  const int tot4 = b4_2 + B*3*100;             // + s2 (100800)

  __shared__ unsigned umask[16];               // 512 bits: block's 512 pixels
  __shared__ int   pairs[1600];                // (localbit<<13)|row
  __shared__ int   paircnt;
  __shared__ float s0lds[512];                 // S0 per local pixel
  __shared__ float robj[4], rcorr[4];

  if (tid < 16) umask[tid] = 0u;
  if (tid == 0) paircnt = 0;
  if (blockIdx.x == 0)
    for (int k = tid; k < ACC_TOTAL; k += 256) acc[k] = 0.f;
  __syncthreads();

  // ---- build mask + pair list from targets (identical valid/cell math to k_rows) ----
  for (int n = tid; n < N; n += 256) {
    int   b  = min(max((int)tgt[n*TCOLS+0], 0), B-1);
    float tx = tgt[n*TCOLS+2], ty = tgt[n*TCOLS+3];
    int base4 = 0;
    #pragma unroll
    for (int s = 0; s < 3; ++s) {
      int w  = (s==0)?80:((s==1)?40:20);
      int hw = w*w, pc4 = hw>>2;
      float fw = (float)w;
      float gx = tx*fw, gy = ty*fw;
      if (gx >= 0.f && gx < fw && gy >= 0.f && gy < fw) {
        int gi = min(max((int)floorf(gx),0), w-1);
        int gj = min(max((int)floorf(gy),0), w-1);
        int cell = gj*w + gi;
        for (int a = 0; a < 3; ++a) {
          int col4 = base4 + (b*3+a)*pc4 + (cell>>2);
          int loc  = col4 - c0;
          if (loc >= 0 && loc < 128) {
            int bit = loc*4 + (cell&3);
            atomicOr(&umask[bit>>5], 1u<<(bit&31));
            int idx = atomicAdd(&paircnt, 1);
            if (idx < 1600) pairs[idx] = (bit<<13) | (s*(N*3) + n*3 + a);
          }
        }
      }
      base4 += B*3*pc4;
    }
  }
  __syncthreads();

  // ---- stream ----
  const int  col4 = c0 + (tid>>1);
  const int  half = tid & 1;
  const int  loc  = col4 - c0;
  float  obj = 0.f, corr = 0.f;
  float4 S0  = {0.f, 0.f, 0.f, 0.f};
  if (col4 < tot4) {
    int hw, pc4, i;
    const float* pred;
    if (col4 < b4_1)      { hw=6400; pc4=1600; i=col4;      pred=p0; }
    else if (col4 < b4_2) { hw=1600; pc4=400;  i=col4-b4_1; pred=p1; }
    else                  { hw=400;  pc4=100;  i=col4-b4_2; pred=p2; }
    int ba  = i / pc4;
    int pix = (i - ba*pc4) * 4;
    int b   = ba / 3, a = ba - b*3;
    float inv = 1.f / (float)(B*3*hw);
    size_t base = (size_t)(b*255 + a*85)*hw + pix;
    unsigned m = (umask[loc>>3] >> ((loc&7)*4)) & 0xFu;

    if (half == 0) {
      float4 xo = *(const float4*)(pred + base + (size_t)4*hw);   // obj channel
      obj = (fbce0(xo.x)+fbce0(xo.y)+fbce0(xo.z)+fbce0(xo.w)) * inv;
      if (m) {
        float cs = 0.f;
        if (m&1) cs += xo.x;
        if (m&2) cs += xo.y;
        if (m&4) cs += xo.z;
        if (m&8) cs += xo.w;
        corr = -cs * inv;                     // bce(x,1)-bce(x,0) = -x
      }
      #pragma unroll 4
      for (int ch = 5; ch < 45; ++ch) {
        float4 x4 = *(const float4*)(pred + base + (size_t)ch*hw);
        if (m) {
          if (m&1) S0.x += ffoc(fbce0(x4.x));
          if (m&2) S0.y += ffoc(fbce0(x4.y));
          if (m&4) S0.z += ffoc(fbce0(x4.z));
          if (m&8) S0.w += ffoc(fbce0(x4.w));
        }
      }
    } else {
      #pragma unroll 4
      for (int ch = 45; ch < 85; ++ch) {
        float4 x4 = *(const float4*)(pred + base + (size_t)ch*hw);
        if (m) {
          if (m&1) S0.x += ffoc(fbce0(x4.x));
          if (m&2) S0.y += ffoc(fbce0(x4.y));
          if (m&4) S0.z += ffoc(fbce0(x4.z));
          if (m&8) S0.w += ffoc(fbce0(x4.w));
        }
      }
    }
  }
  // combine channel halves (partner lane tid^1)
  S0.x += __shfl_xor(S0.x, 1, 64);
  S0.y += __shfl_xor(S0.y, 1, 64);
  S0.z += __shfl_xor(S0.z, 1, 64);
  S0.w += __shfl_xor(S0.w, 1, 64);
  if (col4 < tot4 && half == 0)
    *(float4*)&s0lds[loc*4] = S0;            // 16B-aligned LDS store

  for (int off = 32; off > 0; off >>= 1) {
    obj  += __shfl_xor(obj,  off, 64);
    corr += __shfl_xor(corr, off, 64);
  }
  if ((tid & 63) == 0) { robj[tid>>6] = obj; rcorr[tid>>6] = corr; }
  __syncthreads();

  // route S0 to rows (each row's cell owned by exactly one block)
  int pcnt = min(paircnt, 1600);
  for (int ii = tid; ii < pcnt; ii += 256) {
    int pk = pairs[ii];
    s0row[pk & 8191] = s0lds[pk >> 13];
  }
  if (tid == 0) {
    slot[0] = robj[0] + robj[1] + robj[2] + robj[3];
    slot[1] = rcorr[0] + rcorr[1] + rcorr[2] + rcorr[3];
  }
}

// Tiny gather: one thread per (scale,target,anchor) row — 7 lines each
// (4 box + 1 cls + S0). rs = S0 + focal1(x_cls) - focal0(x_cls).
__global__ __launch_bounds__(256)
void k_rows(const float* __restrict__ p0, const float* __restrict__ p1,
            const float* __restrict__ p2, const float* __restrict__ tgt,
            int N, int B, float* __restrict__ ws) {
  __shared__ float l_box[3], l_cls[3], l_nv[3];
  float* acc   = ws;
  float* s0row = ws + S0OFF;
  const int tid = threadIdx.x;
  if (tid < 3) { l_box[tid]=0.f; l_cls[tid]=0.f; l_nv[tid]=0.f; }
  __syncthreads();

  int r = blockIdx.x * 256 + tid;
  int nrows = 9 * N;
  if (r < nrows) {
    int s   = r / (3*N);
    int rem = r - s*3*N;
    int n   = rem / 3;
    int a   = rem - n*3;
    int w   = (s==0)?80:((s==1)?40:20);
    int hw  = w*w;
    const float* pred = (s==0)?p0:((s==1)?p1:p2);
    float fw = (float)w;
    float gx = tgt[n*TCOLS+2]*fw, gy = tgt[n*TCOLS+3]*fw;
    if (gx >= 0.f && gx < fw && gy >= 0.f && gy < fw) {
      float gw = tgt[n*TCOLS+4]*fw, gh = tgt[n*TCOLS+5]*fw;
      int gi  = min(max((int)floorf(gx),0), w-1);
      int gj  = min(max((int)floorf(gy),0), w-1);
      int b   = min(max((int)tgt[n*TCOLS+0], 0), B-1);
      int cls = min(max((int)tgt[n*TCOLS+1], 0), NC-1);
      size_t base = (size_t)(b*255 + a*85)*hw + (size_t)(gj*w + gi);

      // 7 independent loads (MLP)
      float bx = pred[base];
      float by = pred[base + (size_t)hw];
      float bw = pred[base + 2*(size_t)hw];
      float bh = pred[base + 3*(size_t)hw];
      float xr = pred[base + (size_t)(5 + cls)*hw];
      float s0v = s0row[r];

      float rs = s0v + ffoc(fbce1(xr)) - ffoc(fbce0(xr));

      float sx = 1.f/(1.f + __expf(-bx));
      float sy = 1.f/(1.f + __expf(-by));
      float sw = 1.f/(1.f + __expf(-bw));
      float sh = 1.f/(1.f + __expf(-bh));
      float px = sx*2.f - 0.5f, py = sy*2.f - 0.5f;
      float aw = c_anch[s][a][0], ah = c_anch[s][a][1];
      float pw = (sw*2.f)*(sw*2.f)*aw, ph = (sh*2.f)*(sh*2.f)*ah;
      float txf = gx - floorf(gx), tyf = gy - floorf(gy);
      // iou_cxcywh replicated (eps on heights + union only)
      float b1x1 = px - pw*0.5f, b1x2 = px + pw*0.5f;
      float b1y1 = py - ph*0.5f, b1y2 = py + ph*0.5f;
      float b2x1 = txf - gw*0.5f, b2x2 = txf + gw*0.5f;
      float b2y1 = tyf - gh*0.5f, b2y2 = tyf + gh*0.5f;
      float iw = fmaxf(fminf(b1x2, b2x2) - fmaxf(b1x1, b2x1), 0.f);
      float ih = fmaxf(fminf(b1y2, b2y2) - fmaxf(b1y1, b2y1), 0.f);
      float inter = iw * ih;
      float w1 = b1x2 - b1x1, h1 = b1y2 - b1y1 + 1e-7f;
      float w2 = b2x2 - b2x1, h2 = b2y2 - b2y1 + 1e-7f;
      float uni = w1*h1 + w2*h2 - inter + 1e-7f;
      float iou = inter / uni;

      atomicAdd(&l_box[s], 1.f - iou);
      atomicAdd(&l_cls[s], rs);
      atomicAdd(&l_nv[s],  1.f);
      atomicAdd(&acc[ACC_SEG +        s*NC + cls], rs);   // spread, overlapped
      atomicAdd(&acc[ACC_SEG + 3*NC + s*NC + cls], 1.f);
    }
  }
  __syncthreads();
  if (tid < 3) {
    int s = tid; float v;
    v = l_box[s]; if (v != 0.f) atomicAdd(&acc[ACC_BOX(s)], v);
    v = l_cls[s]; if (v != 0.f) atomicAdd(&acc[ACC_CLS(s)], v);
    v = l_nv [s]; if (v != 0.f) atomicAdd(&acc[ACC_NV (s)], v);
  }
}

__global__ __launch_bounds__(512)
void k_final(const float* __restrict__ ws, int nblk, float* __restrict__ out) {
  __shared__ float red[8][2];
  __shared__ float sOC[2];
  const int tid  = threadIdx.x;
  const int lane = tid & 63;
  const int wv   = tid >> 6;
  const float* acc = ws;

  float v0 = 0.f, v1 = 0.f;
  for (int b = tid; b < nblk; b += 512) {
    const float* slot = ws + SLOTOFF + b*16;   // one 64 B line per thread
    v0 += slot[0]; v1 += slot[1];
  }
  for (int off = 32; off > 0; off >>= 1) {
    v0 += __shfl_xor(v0, off, 64);
    v1 += __shfl_xor(v1, off, 64);
  }
  if (lane == 0) { red[wv][0] = v0; red[wv][1] = v1; }
  __syncthreads();
  if (tid < 2) {
    float t = 0.f;
    for (int k = 0; k < 8; ++k) t += red[k][tid];
    sOC[tid] = t;
  }
  __syncthreads();

  if (tid == 0) {
    float lo = sOC[0] + sOC[1];
    float lb = 0.f, lc = 0.f;
    for (int s = 0; s < 3; ++s) {
      float nv  = acc[ACC_NV(s)];
      float nvm = fmaxf(nv, 1.f);
      if (nv > 0.f) {
        lb += acc[ACC_BOX(s)] / nvm * 7.5f;                 // BOX_GAIN
        lc += acc[ACC_CLS(s)] / (nvm * (float)NC) * 0.5f;   // CLS_GAIN
      }
    }
    out[0] = lb + lc + lo;
    out[1] = lb;
    out[2] = lc;
    out[3] = lo;
  }
  if (tid < NC) {
    float pc = 0.f;
    for (int s = 0; s < 3; ++s) {
      float cnt = acc[ACC_SEG + 3*NC + s*NC + tid];
      if (cnt > 0.f)
        pc += acc[ACC_SEG + s*NC + tid] / (fmaxf(cnt, 1.f) * (float)NC) * 0.5f;
    }
    out[4 + tid] = pc;
  }
}

extern "C" void kernel_launch(void* const* d_in, const int* in_sizes, int n_in,
                              void* d_out, int out_size, void* d_ws, size_t ws_size,
                              hipStream_t stream) {
  const float* p0  = (const float*)d_in[0];
  const float* p1  = (const float*)d_in[1];
  const float* p2  = (const float*)d_in[2];
  const float* tgt = (const float*)d_in[3];
  int N = in_sizes[3] / TCOLS;             // 800 targets
  int B = in_sizes[0] / (255 * 6400);      // 16
  float* out = (float*)d_out;
  float* ws  = (float*)d_ws;               // ~85 KB used

  int tot4   = B * 3 * (1600 + 400 + 100); // 100800 float4-columns
  int nchunk = (tot4 + 127) / 128;         // 788 stream blocks
  int nrows  = 9 * N;                      // 7200
  int rb     = (nrows + 255) / 256;        // 29 row blocks

  k_stream<<<nchunk, 256, 0, stream>>>(p0, p1, p2, tgt, N, B, ws);
  k_rows  <<<rb,     256, 0, stream>>>(p0, p1, p2, tgt, N, B, ws);
  k_final <<<1,      512, 0, stream>>>(ws, nchunk, out);
}

// Round 16
// 35.570 us; speedup vs baseline: 2.3824x; 2.3824x over previous
//
#include <hip/hip_runtime.h>
#include <math.h>

#define NC 80
#define TCOLS 6      // targets: [b, cls, x, y, w, h]
#define RPB 15       // rows per block (waves 0..14; wave 15 idle)

// ANCHORS[scale][anchor][wh]
__device__ __constant__ float c_anch[3][3][2] = {
  {{10.f,13.f},{16.f,30.f},{33.f,23.f}},
  {{30.f,61.f},{62.f,45.f},{59.f,119.f}},
  {{116.f,90.f},{156.f,198.f},{373.f,326.f}}
};

// acc layout (floats) — each hot scalar on its own 64 B line
#define ACC_CORR   0                    // obj correction sum(-x/cnt)
#define ACC_OBJ    16                   // obj background stream sum
#define ACC_BOX(s) (32 + 16*(s))
#define ACC_CLS(s) (80 + 16*(s))
#define ACC_NV(s)  (128 + 16*(s))
#define ACC_SEG    176                  // [3*NC sums][3*NC counts]
#define ACC_TOTAL  (176 + 6*NC)         // 656 floats

// fast transcendentals: v_exp/v_log/v_sqrt; abs err ~1e-6 << 0.47 threshold
__device__ __forceinline__ float fbce0(float x) {   // bce(x,0)
  return fmaxf(x, 0.f) + __logf(1.f + __expf(-fabsf(x)));
}
__device__ __forceinline__ float fbce(float x, float t) {
  return fmaxf(x, 0.f) - x * t + __logf(1.f + __expf(-fabsf(x)));
}
__device__ __forceinline__ float ffocal(float x, float t) {
  float ce = fbce(x, t);
  float u  = 1.f - __expf(-ce);
  return u * __builtin_amdgcn_sqrtf(u) * ce;        // (1-e^-ce)^1.5 * ce
}

__global__ void k_init(float* __restrict__ acc) {
  for (int k = threadIdx.x; k < ACC_TOTAL; k += 256) acc[k] = 0.f;
}

// blocks [0, RB):        rows — one 64-lane wave per (scale,target,anchor), 15/block
// blocks [RB, RB+B):     corr — per-image LDS-bitmask dedup (bce(x,1)-bce(x,0) = -x)
// blocks [RB+B, grid):   obj background stream -> atomicAdd into ACC_OBJ
__global__ __launch_bounds__(1024, 8)
void k_fused(const float* __restrict__ p0, const float* __restrict__ p1,
             const float* __restrict__ p2, const float* __restrict__ tgt,
             int N, int B, int RB, int OBJB, float* __restrict__ acc) {
  const int bid = blockIdx.x;
  const int tid = threadIdx.x;
  __shared__ float red[16];

  if (bid < RB) {
    // ---------------- rows role ----------------
    __shared__ float l_box[3], l_cls[3], l_nv[3];
    if (tid < 3) { l_box[tid]=0.f; l_cls[tid]=0.f; l_nv[tid]=0.f; }
    __syncthreads();
    int wv    = tid >> 6;
    int lane  = tid & 63;
    int row   = bid * RPB + wv;
    int nrows = 9 * N;
    if (wv < RPB && row < nrows) {
      int rps = N * 3;
      int s   = row / rps;
      int rem = row - s * rps;
      int n   = rem / 3;
      int a   = rem - n * 3;
      int w   = (s == 0) ? 80 : ((s == 1) ? 40 : 20);
      int hw  = w * w;
      const float* pred = (s == 0) ? p0 : ((s == 1) ? p1 : p2);
      float fw = (float)w;
      float gx = tgt[n*TCOLS + 2] * fw, gy = tgt[n*TCOLS + 3] * fw;
      if (gx >= 0.f && gx < fw && gy >= 0.f && gy < fw) {   // wave-uniform
        float gw = tgt[n*TCOLS + 4] * fw, gh = tgt[n*TCOLS + 5] * fw;
        int gi  = min(max((int)floorf(gx), 0), w - 1);
        int gj  = min(max((int)floorf(gy), 0), w - 1);
        int b   = min(max((int)tgt[n*TCOLS + 0], 0), B - 1);
        int cls = min(max((int)tgt[n*TCOLS + 1], 0), NC - 1);
        size_t base = (size_t)(b*255 + a*85) * hw + (size_t)(gj*w + gi);

        // issue all global loads up-front (MLP); predicate extra lanes
        float x0  = pred[base + (size_t)(5 + lane) * hw];                      // cls c = lane
        float x1  = (lane < 16) ? pred[base + (size_t)(69 + lane) * hw] : 0.f; // cls 64+lane
        float bxv = (lane < 4)  ? pred[base + (size_t)lane * hw] : 0.f;

        float rs = ffocal(x0, (lane == cls) ? 1.f : 0.f);
        if (lane < 16) rs += ffocal(x1, ((64 + lane) == cls) ? 1.f : 0.f);
        for (int off = 32; off > 0; off >>= 1) rs += __shfl_xor(rs, off, 64);

        float bx = __shfl(bxv, 0, 64), by = __shfl(bxv, 1, 64);
        float bw = __shfl(bxv, 2, 64), bh = __shfl(bxv, 3, 64);
        if (lane == 0) {
          float sx = 1.f/(1.f + __expf(-bx));
          float sy = 1.f/(1.f + __expf(-by));
          float sw = 1.f/(1.f + __expf(-bw));
          float sh = 1.f/(1.f + __expf(-bh));
          float px = sx*2.f - 0.5f, py = sy*2.f - 0.5f;
          float aw = c_anch[s][a][0], ah = c_anch[s][a][1];
          float pw = (sw*2.f)*(sw*2.f)*aw, ph = (sh*2.f)*(sh*2.f)*ah;
          float txf = gx - floorf(gx), tyf = gy - floorf(gy);
          // iou_cxcywh replicated (eps on heights + union only)
          float b1x1 = px - pw*0.5f, b1x2 = px + pw*0.5f;
          float b1y1 = py - ph*0.5f, b1y2 = py + ph*0.5f;
          float b2x1 = txf - gw*0.5f, b2x2 = txf + gw*0.5f;
          float b2y1 = tyf - gh*0.5f, b2y2 = tyf + gh*0.5f;
          float iw = fmaxf(fminf(b1x2, b2x2) - fmaxf(b1x1, b2x1), 0.f);
          float ih = fmaxf(fminf(b1y2, b2y2) - fmaxf(b1y1, b2y1), 0.f);
          float inter = iw * ih;
          float w1 = b1x2 - b1x1, h1 = b1y2 - b1y1 + 1e-7f;
          float w2 = b2x2 - b2x1, h2 = b2y2 - b2y1 + 1e-7f;
          float uni = w1*h1 + w2*h2 - inter + 1e-7f;
          float iou = inter / uni;

          atomicAdd(&l_box[s], 1.f - iou);
          atomicAdd(&l_cls[s], rs);
          atomicAdd(&l_nv[s],  1.f);
          atomicAdd(&acc[ACC_SEG +        s*NC + cls], rs);   // overlaps gather latency
          atomicAdd(&acc[ACC_SEG + 3*NC + s*NC + cls], 1.f);
        }
      }
    }
    __syncthreads();
    if (tid < 3) {
      int s = tid; float v;
      v = l_box[s]; if (v != 0.f) atomicAdd(&acc[ACC_BOX(s)], v);
      v = l_cls[s]; if (v != 0.f) atomicAdd(&acc[ACC_CLS(s)], v);
      v = l_nv [s]; if (v != 0.f) atomicAdd(&acc[ACC_NV (s)], v);
    }
  } else if (bid < RB + B) {
    // ------- corr role: one block per image, LDS-bitmask dedup -------
    const int bimg = bid - RB;
    __shared__ unsigned cmask[264];     // 8448 bits >= 6400+1600+400 cells
    for (int k = tid; k < 264; k += 1024) cmask[k] = 0u;
    __syncthreads();
    float corr = 0.f;
    for (int n = tid; n < N; n += 1024) {
      int b = min(max((int)tgt[n*TCOLS + 0], 0), B - 1);
      if (b != bimg) continue;
      float tx = tgt[n*TCOLS + 2], ty = tgt[n*TCOLS + 3];
      #pragma unroll
      for (int s = 0; s < 3; ++s) {
        int w  = (s == 0) ? 80 : ((s == 1) ? 40 : 20);
        int hw = w * w;
        float fw = (float)w;
        float gx = tx * fw, gy = ty * fw;
        if (!(gx >= 0.f && gx < fw && gy >= 0.f && gy < fw)) continue;
        int gi = min(max((int)floorf(gx), 0), w - 1);
        int gj = min(max((int)floorf(gy), 0), w - 1);
        int cell = gj * w + gi;
        int bit  = ((s == 0) ? 0 : ((s == 1) ? 6400 : 8000)) + cell;
        unsigned m = 1u << (bit & 31);
        unsigned old = atomicOr(&cmask[bit >> 5], m);
        if (!(old & m)) {               // owner of distinct (s, cell) in this image
          const float* pred = (s == 0) ? p0 : ((s == 1) ? p1 : p2);
          float inv = 1.f / (float)(B * 3 * hw);
          float sum = pred[(size_t)(bimg*255 +   4) * hw + cell]
                    + pred[(size_t)(bimg*255 +  89) * hw + cell]
                    + pred[(size_t)(bimg*255 + 174) * hw + cell];
          corr -= sum * inv;            // bce(x,1)-bce(x,0) = -x
        }
      }
    }
    for (int off = 32; off > 0; off >>= 1) corr += __shfl_xor(corr, off, 64);
    if ((tid & 63) == 0) red[tid >> 6] = corr;
    __syncthreads();
    if (tid == 0) {
      float t = 0.f;
      for (int k = 0; k < 16; ++k) t += red[k];
      if (t != 0.f) atomicAdd(&acc[ACC_CORR], t);
    }
  } else {
    // ---------------- obj background stream role ----------------
    const int ob = bid - RB - B;
    const int n0 = B*3*6400, n1 = B*3*1600, n2 = B*3*400;
    const int total4 = (n0 + n1 + n2) >> 2;
    const float i0 = 1.f/(float)n0, i1 = 1.f/(float)n1, i2 = 1.f/(float)n2;
    float local = 0.f;
    for (int i = ob * 1024 + tid; i < total4; i += OBJB * 1024) {
      int e = i << 2;
      const float* pred; int idx, hw; float inv;
      if (e < n0)         { pred = p0; idx = e;           hw = 6400; inv = i0; }
      else if (e < n0+n1) { pred = p1; idx = e - n0;      hw = 1600; inv = i1; }
      else                { pred = p2; idx = e - n0 - n1; hw = 400;  inv = i2; }
      int ba = idx / hw, pix = idx - ba * hw;     // pix..pix+3 in-plane (hw%4==0)
      int b = ba / 3, a = ba - b * 3;
      const float4 x4 = *(const float4*)&pred[(size_t)(b*255 + a*85 + 4) * hw + pix];
      local += (fbce0(x4.x) + fbce0(x4.y) + fbce0(x4.z) + fbce0(x4.w)) * inv;
    }
    for (int off = 32; off > 0; off >>= 1) local += __shfl_xor(local, off, 64);
    if ((tid & 63) == 0) red[tid >> 6] = local;
    __syncthreads();
    if (tid == 0) {
      float t = 0.f;
      for (int k = 0; k < 16; ++k) t += red[k];
      atomicAdd(&acc[ACC_OBJ], t);
    }
  }
}

__global__ void k_final(const float* __restrict__ acc, float* __restrict__ out) {
  int t = threadIdx.x;                    // 128 threads
  if (t == 0) {
    float lo = acc[ACC_OBJ] + acc[ACC_CORR];
    float lb = 0.f, lc = 0.f;
    for (int s = 0; s < 3; ++s) {
      float nv  = acc[ACC_NV(s)];
      float nvm = fmaxf(nv, 1.f);
      if (nv > 0.f) {
        lb += acc[ACC_BOX(s)] / nvm * 7.5f;                 // BOX_GAIN
        lc += acc[ACC_CLS(s)] / (nvm * (float)NC) * 0.5f;   // CLS_GAIN
      }
    }
    out[0] = lb + lc + lo;
    out[1] = lb;
    out[2] = lc;
    out[3] = lo;
  }
  if (t < NC) {
    float pc = 0.f;
    for (int s = 0; s < 3; ++s) {
      float cnt = acc[ACC_SEG + 3*NC + s*NC + t];
      if (cnt > 0.f)
        pc += acc[ACC_SEG + s*NC + t] / (fmaxf(cnt, 1.f) * (float)NC) * 0.5f;
    }
    out[4 + t] = pc;
  }
}

extern "C" void kernel_launch(void* const* d_in, const int* in_sizes, int n_in,
                              void* d_out, int out_size, void* d_ws, size_t ws_size,
                              hipStream_t stream) {
  const float* p0  = (const float*)d_in[0];
  const float* p1  = (const float*)d_in[1];
  const float* p2  = (const float*)d_in[2];
  const float* tgt = (const float*)d_in[3];
  int N = in_sizes[3] / TCOLS;             // 800 targets
  int B = in_sizes[0] / (255 * 6400);      // 16
  float* out = (float*)d_out;
  float* acc = (float*)d_ws;

  int nrows = 9 * N;                       // 7200
  int RB   = (nrows + RPB - 1) / RPB;      // 480 rows-blocks (dispatch first)
  int OBJB = 512 - RB - B;                 // 16 obj blocks
  if (OBJB < 1) OBJB = 1;
  int grid = RB + B + OBJB;                // 512 = 2 blocks/CU exactly

  k_init <<<1, 256, 0, stream>>>(acc);
  k_fused<<<grid, 1024, 0, stream>>>(p0, p1, p2, tgt, N, B, RB, OBJB, acc);
  k_final<<<1, 128, 0, stream>>>(acc, out);
}